// Round 6
// baseline (618.505 us; speedup 1.0000x reference)
//
#include <hip/hip_runtime.h>

typedef _Float16 h2 __attribute__((ext_vector_type(2)));

#define B_ 4096
#define T_ 128
#define F_ 64
#define H_ 32
#define G_ 128  // 4*H

__device__ __forceinline__ float sigmoid_f(float z) {
    return __builtin_amdgcn_rcpf(1.0f + __expf(-z));
}

// v_dot2_f32_f16: 2 f16 MACs, fp32 accumulate, full VALU rate.
__device__ __forceinline__ float dot2(h2 a, h2 b, float c) {
#if __has_builtin(__builtin_amdgcn_fdot2)
    return __builtin_amdgcn_fdot2(a, b, c, false);
#else
    return c + (float)a.x * (float)b.x + (float)a.y * (float)b.y;
#endif
}

// R2-R5 lesson: if structural register demand exceeds ~128, the gfx950
// allocator parks the overflow in AGPRs for the kernel lifetime (1 wave/SIMD,
// +accvgpr copy per use; 4 counter-measures all failed). So: TWO waves per
// batch element, ONE gate column per lane. Per-lane weights: enc 48 h2, dec 32
// h2 -> peak live ~100 regs, comfortably under 128.
//
// Lane map (tid 0..127): wv=tid>>6, l=tid&63, q=l>>4 (gate i,f,g,o), jp=l&15,
// j=16*wv+jp (hidden idx), col=32*q+j (gate column in [0,128)).
// Gate combine via 3 intra-wave shfl_xor: for q0: a=i, v1(^16)=f, v2(^32)=g,
// v3(^48)=o -> c=f*c+i*g, h=o*relu(c). Only q0 lanes keep real c / publish h.
// Cross-wave h broadcast: double-buffered 32-f16 LDS row, ONE barrier/step.
// Race audit: h_t in buf[t&1]; writes to buf[(t+1)&1] can't collide with
// reads of buf[t&1] (sealed by barrier t). x stage: wave0 writes
// xbuf[(t+1)&1] at step t; last read of that buffer ended before barrier(t-1).
extern "C" __global__ __launch_bounds__(128)
void lstm_ae(const float* __restrict__ x,
             const float* __restrict__ We,
             const float* __restrict__ Ue,
             const float* __restrict__ be,
             const float* __restrict__ Wd,
             const float* __restrict__ Ud,
             const float* __restrict__ bd,
             const float* __restrict__ Wout,
             const float* __restrict__ bout,
             float* __restrict__ out)
{
    const int tid = threadIdx.x;     // 0..127
    const int wv  = tid >> 6;        // wave 0/1
    const int l   = tid & 63;        // lane in wave
    const int q   = l >> 4;          // gate group: 0=i 1=f 2=g 3=o
    const int jp  = l & 15;
    const int j   = (wv << 4) | jp;  // hidden index 0..31
    const int col = (q << 5) | j;    // gate column 0..127
    const int b   = blockIdx.x;

    __shared__ __align__(16) _Float16 xbufh[2][64];  // double-buffered x row (f16)
    __shared__ __align__(16) _Float16 hbufh[2][32];  // double-buffered h (f16)

    // ---- encoder weights: one gate column per lane (48 h2 regs) ----
    h2 we[32], ue[16];
#pragma unroll
    for (int k = 0; k < 32; ++k) {
        h2 v = {(_Float16)We[(2 * k) * G_ + col], (_Float16)We[(2 * k + 1) * G_ + col]};
        we[k] = v;
    }
#pragma unroll
    for (int k = 0; k < 16; ++k) {
        h2 v = {(_Float16)Ue[(2 * k) * G_ + col], (_Float16)Ue[(2 * k + 1) * G_ + col]};
        ue[k] = v;
    }
    const float bz = be[col];

    const float* xrow = x + (size_t)b * (T_ * F_);

    // stage x[0] (wave 0)
    if (wv == 0) xbufh[0][l] = (_Float16)xrow[l];
    __syncthreads();

    float4 hf4[4];  // h as 32 f16 (16 h2); starts at 0
#pragma unroll
    for (int k = 0; k < 4; ++k) hf4[k] = make_float4(0.f, 0.f, 0.f, 0.f);
    float c = 0.0f;

    // =========================== encoder scan ===========================
#pragma unroll 1
    for (int t = 0; t < T_; ++t) {
        // stage x_{t+1} (wave 0; clamped index)
        if (wv == 0) {
            const int tn = (t + 1 < T_) ? (t + 1) : (T_ - 1);
            xbufh[(t + 1) & 1][l] = (_Float16)xrow[tn * F_ + l];
        }

        float z0 = 0.f, z1 = 0.f, z2 = 0.f, z3 = 0.f;
        const float4* xb = (const float4*)&xbufh[t & 1][0];  // 8 x float4 = 64 f16
#pragma unroll
        for (int p = 0; p < 8; ++p) {
            float4 xq = xb[p];               // wave-uniform broadcast read
            const h2* xh = (const h2*)&xq;
            int k = 4 * p;
            z0 = dot2(xh[0], we[k + 0], z0);
            z1 = dot2(xh[1], we[k + 1], z1);
            z2 = dot2(xh[2], we[k + 2], z2);
            z3 = dot2(xh[3], we[k + 3], z3);
        }
        const h2* hh = (const h2*)hf4;       // h_{t-1}
#pragma unroll
        for (int p = 0; p < 16; p += 4) {
            z0 = dot2(hh[p + 0], ue[p + 0], z0);
            z1 = dot2(hh[p + 1], ue[p + 1], z1);
            z2 = dot2(hh[p + 2], ue[p + 2], z2);
            z3 = dot2(hh[p + 3], ue[p + 3], z3);
        }
        float z = bz + (z0 + z1) + (z2 + z3);

        float a = (q == 2) ? fmaxf(z, 0.f) : sigmoid_f(z);
        float v1 = __shfl_xor(a, 16, 64);
        float v2 = __shfl_xor(a, 32, 64);
        float v3 = __shfl_xor(v1, 32, 64);
        // q0 roles: a=i, v1=f, v2=g, v3=o (other groups compute garbage, never used)
        c = fmaf(v1, c, a * v2);
        float hval = v3 * fmaxf(c, 0.f);
        if (q == 0) hbufh[t & 1][j] = (_Float16)hval;   // publish h_t
        __syncthreads();
        const float4* hb = (const float4*)&hbufh[t & 1][0];
        hf4[0] = hb[0]; hf4[1] = hb[1]; hf4[2] = hb[2]; hf4[3] = hb[3];
    }
    // hf4 now holds h_T (f16) in every lane

    // ============ decoder constant input: zd = bd + hT@Wd (once) ============
    float zd = bd[col];
    {
        const h2* hh = (const h2*)hf4;
#pragma unroll
        for (int k = 0; k < 16; ++k) {
            zd = fmaf((float)hh[k].x, Wd[(2 * k) * G_ + col], zd);
            zd = fmaf((float)hh[k].y, Wd[(2 * k + 1) * G_ + col], zd);
        }
    }

    // ---- decoder weights (encoder regs dead): Ud col + Wout col (32 h2) ----
    h2 ud[16], wo[16];
#pragma unroll
    for (int k = 0; k < 16; ++k) {
        h2 v = {(_Float16)Ud[(2 * k) * G_ + col], (_Float16)Ud[(2 * k + 1) * G_ + col]};
        ud[k] = v;
    }
#pragma unroll
    for (int k = 0; k < 16; ++k) {
        h2 v = {(_Float16)Wout[(2 * k) * F_ + l], (_Float16)Wout[(2 * k + 1) * F_ + l]};
        wo[k] = v;
    }
    const float bo = bout[l];

#pragma unroll
    for (int k = 0; k < 4; ++k) hf4[k] = make_float4(0.f, 0.f, 0.f, 0.f);
    c = 0.f;

    float* orow = out + (size_t)b * (T_ * F_);

    // ================= decoder scan + fused out projection =================
#pragma unroll 1
    for (int t = 0; t < T_; ++t) {
        const h2* hh = (const h2*)hf4;       // h_{t-1}
        float z0 = 0.f, z1 = 0.f, z2 = 0.f, z3 = 0.f;
#pragma unroll
        for (int p = 0; p < 16; p += 4) {
            z0 = dot2(hh[p + 0], ud[p + 0], z0);
            z1 = dot2(hh[p + 1], ud[p + 1], z1);
            z2 = dot2(hh[p + 2], ud[p + 2], z2);
            z3 = dot2(hh[p + 3], ud[p + 3], z3);
        }
        float z = zd + (z0 + z1) + (z2 + z3);

        float a = (q == 2) ? fmaxf(z, 0.f) : sigmoid_f(z);
        float v1 = __shfl_xor(a, 16, 64);
        float v2 = __shfl_xor(a, 32, 64);
        float v3 = __shfl_xor(v1, 32, 64);
        c = fmaf(v1, c, a * v2);
        float hval = v3 * fmaxf(c, 0.f);
        if (q == 0) hbufh[t & 1][j] = (_Float16)hval;   // publish h_t
        __syncthreads();
        const float4* hb = (const float4*)&hbufh[t & 1][0];
        hf4[0] = hb[0]; hf4[1] = hb[1]; hf4[2] = hb[2]; hf4[3] = hb[3];

        // out[b,t,f]: wave 0 computes+stores (f = l); wave 1 skips (wave-uniform)
        if (wv == 0) {
            const h2* ht = (const h2*)hf4;   // h_t
            float o0 = bo, o1 = 0.f, o2 = 0.f, o3 = 0.f;
#pragma unroll
            for (int p = 0; p < 16; p += 4) {
                o0 = dot2(ht[p + 0], wo[p + 0], o0);
                o1 = dot2(ht[p + 1], wo[p + 1], o1);
                o2 = dot2(ht[p + 2], wo[p + 2], o2);
                o3 = dot2(ht[p + 3], wo[p + 3], o3);
            }
            orow[t * F_ + l] = (o0 + o1) + (o2 + o3);
        }
    }
}

extern "C" void kernel_launch(void* const* d_in, const int* in_sizes, int n_in,
                              void* d_out, int out_size, void* d_ws, size_t ws_size,
                              hipStream_t stream) {
    (void)in_sizes; (void)n_in; (void)d_ws; (void)ws_size; (void)out_size;
    const float* x    = (const float*)d_in[0];
    const float* We   = (const float*)d_in[1];
    const float* Ue   = (const float*)d_in[2];
    const float* be   = (const float*)d_in[3];
    const float* Wd   = (const float*)d_in[4];
    const float* Ud   = (const float*)d_in[5];
    const float* bd   = (const float*)d_in[6];
    const float* Wout = (const float*)d_in[7];
    const float* bout = (const float*)d_in[8];
    float* out = (float*)d_out;

    dim3 grid(B_), block(128);
    hipLaunchKernelGGL(lstm_ae, grid, block, 0, stream,
                       x, We, Ue, be, Wd, Ud, bd, Wout, bout, out);
}